// Round 1
// baseline (329.484 us; speedup 1.0000x reference)
//
#include <hip/hip_runtime.h>
#include <cstddef>

#define NN 10
#define NB 512
#define NP 1152
#define CI 8
#define CO 16
#define BLOCK 256
#define BT 2
#define PT 18   // NP / (BLOCK/4)

__device__ __forceinline__ float wred_sum_pg(float v) {
#pragma unroll
  for (int m = 4; m <= 32; m <<= 1) v += __shfl_xor(v, m);
  return v;
}
__device__ __forceinline__ float wred_max_pg(float v) {
#pragma unroll
  for (int m = 4; m <= 32; m <<= 1) v = fmaxf(v, __shfl_xor(v, m));
  return v;
}

// One block handles one n and BT consecutive batches b.
// Thread map: o4 = (tid&3)*4 (owns o in [o4,o4+4)), pg = tid>>2 (owns p = pg + 64k, k<18).
// u_hat kept entirely in registers: float4 u[BT][PT].
__global__ __launch_bounds__(BLOCK, 2)
void caps_kernel(const float* __restrict__ x, const float* __restrict__ W,
                 float* __restrict__ out) {
  const int tid  = threadIdx.x;
  const int lane = tid & 63;
  const int wid  = tid >> 6;        // wave 0..3
  const int o4   = (tid & 3) << 2;  // 0,4,8,12
  const int pg   = tid >> 2;        // 0..63

  const int bid = blockIdx.x;
  const int n   = bid >> 8;         // 0..9  (256 consecutive blocks share n -> L2 reuse of W[n])
  const int b0  = (bid & 255) * BT;

  __shared__ float sred[BT][4][CO];  // per-wave s partials
  __shared__ float mred[BT][4];      // per-wave max partials
  __shared__ float zred[BT][4];      // per-wave Z partials
  __shared__ float vbuf[BT][CO];     // broadcast v

  float4 u[BT][PT];
  float  bl[BT][PT];

  // ---------------- u_hat = x @ W ----------------
  const float* Wn  = W + (size_t)n * NP * CI * CO + o4;
  const float* xb0 = x + (size_t)b0 * NP * CI;

#pragma unroll
  for (int k = 0; k < PT; ++k) {
    const int p = pg + 64 * k;
    const float* wrow = Wn + p * (CI * CO);
    const float* xr   = xb0 + p * CI;
    float xv0[CI], xv1[CI];
    *(float4*)&xv0[0] = *(const float4*)(xr);
    *(float4*)&xv0[4] = *(const float4*)(xr + 4);
    *(float4*)&xv1[0] = *(const float4*)(xr + NP * CI);
    *(float4*)&xv1[4] = *(const float4*)(xr + NP * CI + 4);
    float4 a0 = make_float4(0.f, 0.f, 0.f, 0.f);
    float4 a1 = make_float4(0.f, 0.f, 0.f, 0.f);
#pragma unroll
    for (int i = 0; i < CI; ++i) {
      const float4 wv = *(const float4*)(wrow + i * CO);
      a0.x = fmaf(xv0[i], wv.x, a0.x);
      a0.y = fmaf(xv0[i], wv.y, a0.y);
      a0.z = fmaf(xv0[i], wv.z, a0.z);
      a0.w = fmaf(xv0[i], wv.w, a0.w);
      a1.x = fmaf(xv1[i], wv.x, a1.x);
      a1.y = fmaf(xv1[i], wv.y, a1.y);
      a1.z = fmaf(xv1[i], wv.z, a1.z);
      a1.w = fmaf(xv1[i], wv.w, a1.w);
    }
    u[0][k] = a0; u[1][k] = a1;
    bl[0][k] = 0.f; bl[1][k] = 0.f;
  }

  float4 vv[BT];
  float  mm[BT], rz[BT];

  // ---------------- dynamic routing (3 iters) ----------------
#pragma unroll 1
  for (int it = 0; it < 3; ++it) {
    if (it > 0) {
      // a[p] = u[p,:] . v ; bl += a   (reduce over 16 o's = 4 lanes x 4 components)
#pragma unroll
      for (int bt = 0; bt < BT; ++bt) {
#pragma unroll
        for (int k = 0; k < PT; ++k) {
          float d = u[bt][k].x * vv[bt].x + u[bt][k].y * vv[bt].y
                  + u[bt][k].z * vv[bt].z + u[bt][k].w * vv[bt].w;
          d += __shfl_xor(d, 1);
          d += __shfl_xor(d, 2);
          bl[bt][k] += d;
        }
      }
      // softmax over p: block max
#pragma unroll
      for (int bt = 0; bt < BT; ++bt) {
        float m = bl[bt][0];
#pragma unroll
        for (int k = 1; k < PT; ++k) m = fmaxf(m, bl[bt][k]);
        m = wred_max_pg(m);
        if (lane == 0) mred[bt][wid] = m;
      }
      __syncthreads();
#pragma unroll
      for (int bt = 0; bt < BT; ++bt)
        mm[bt] = fmaxf(fmaxf(mred[bt][0], mred[bt][1]),
                       fmaxf(mred[bt][2], mred[bt][3]));
      // block sum of exp
#pragma unroll
      for (int bt = 0; bt < BT; ++bt) {
        float z = 0.f;
#pragma unroll
        for (int k = 0; k < PT; ++k) z += __expf(bl[bt][k] - mm[bt]);
        z = wred_sum_pg(z);
        if (lane == 0) zred[bt][wid] = z;
      }
      __syncthreads();
#pragma unroll
      for (int bt = 0; bt < BT; ++bt) {
        const float SZ = zred[bt][0] + zred[bt][1] + zred[bt][2] + zred[bt][3];
        rz[bt] = 1.f / SZ;
      }
    }

    // s[o] = sum_p c[p] * u_hat[p][o]  (partial per thread, then pg-reduce)
#pragma unroll
    for (int bt = 0; bt < BT; ++bt) {
      float4 ps = make_float4(0.f, 0.f, 0.f, 0.f);
      if (it == 0) {
#pragma unroll
        for (int k = 0; k < PT; ++k) {
          ps.x += u[bt][k].x; ps.y += u[bt][k].y;
          ps.z += u[bt][k].z; ps.w += u[bt][k].w;
        }
        const float c = 1.f / (float)NP;
        ps.x *= c; ps.y *= c; ps.z *= c; ps.w *= c;
      } else {
#pragma unroll
        for (int k = 0; k < PT; ++k) {
          const float e = __expf(bl[bt][k] - mm[bt]);
          ps.x = fmaf(e, u[bt][k].x, ps.x);
          ps.y = fmaf(e, u[bt][k].y, ps.y);
          ps.z = fmaf(e, u[bt][k].z, ps.z);
          ps.w = fmaf(e, u[bt][k].w, ps.w);
        }
        ps.x *= rz[bt]; ps.y *= rz[bt]; ps.z *= rz[bt]; ps.w *= rz[bt];
      }
#pragma unroll
      for (int m = 4; m <= 32; m <<= 1) {
        ps.x += __shfl_xor(ps.x, m);
        ps.y += __shfl_xor(ps.y, m);
        ps.z += __shfl_xor(ps.z, m);
        ps.w += __shfl_xor(ps.w, m);
      }
      if (lane < 4) *(float4*)&sred[bt][wid][lane << 2] = ps;
    }
    __syncthreads();

    // finalize: 32 threads -> squash + (broadcast | store)
    if (tid < 32) {
      const int bt = tid >> 4, o = tid & 15;
      float s = sred[bt][0][o] + sred[bt][1][o] + sred[bt][2][o] + sred[bt][3][o];
      float sq = s * s;
#pragma unroll
      for (int m = 1; m <= 8; m <<= 1) sq += __shfl_xor(sq, m);
      const float nrm = sqrtf(sq);
      const float vj  = s * (nrm / (1.f + sq));
      if (it == 2) out[((size_t)n * NB + b0 + bt) * CO + o] = vj;
      else         vbuf[bt][o] = vj;
    }
    if (it < 2) {
      __syncthreads();
#pragma unroll
      for (int bt = 0; bt < BT; ++bt) vv[bt] = *(const float4*)&vbuf[bt][o4];
    }
  }
}

extern "C" void kernel_launch(void* const* d_in, const int* in_sizes, int n_in,
                              void* d_out, int out_size, void* d_ws, size_t ws_size,
                              hipStream_t stream) {
  const float* x = (const float*)d_in[0];
  const float* W = (const float*)d_in[1];
  float* out     = (float*)d_out;
  (void)in_sizes; (void)n_in; (void)out_size; (void)d_ws; (void)ws_size;
  const int grid = NN * (NB / BT);  // 2560 blocks, one per (n, b-pair)
  caps_kernel<<<grid, BLOCK, 0, stream>>>(x, W, out);
}